// Round 1
// baseline (625.622 us; speedup 1.0000x reference)
//
#include <hip/hip_runtime.h>
#include <hip/hip_bf16.h>

#define EMB   1024
#define NHEAD 16
#define HDIM  64
#define BSZ   4
#define SEQ   2048
#define MROWS (BSZ*SEQ)     // 8192
#define NQKV  (3*EMB)       // 3072

typedef __bf16 bf16;
typedef __bf16 bf16v8 __attribute__((ext_vector_type(8)));
typedef float  f32v4  __attribute__((ext_vector_type(4)));

#define MFMA16(a,b,c) __builtin_amdgcn_mfma_f32_16x16x32_bf16((a),(b),(c),0,0,0)

__device__ __forceinline__ void gload_lds16(const bf16* g, bf16* l) {
  __builtin_amdgcn_global_load_lds((const __attribute__((address_space(1))) void*)g,
                                   (__attribute__((address_space(3))) void*)l,
                                   16, 0, 0);
}

// ---------------- scale reduction + ternarize + split ----------------

__global__ void zero2_kernel(float* p) { p[threadIdx.x] = 0.f; }

__global__ void abs_sum_kernel(const float* __restrict__ w, int n, float* out) {
  float s = 0.f;
  for (int i = blockIdx.x * blockDim.x + threadIdx.x; i < n; i += gridDim.x * blockDim.x)
    s += fabsf(w[i]);
  #pragma unroll
  for (int off = 32; off; off >>= 1) s += __shfl_down(s, off, 64);
  __shared__ float red[4];
  int lane = threadIdx.x & 63, wid = threadIdx.x >> 6;
  if (lane == 0) red[wid] = s;
  __syncthreads();
  if (threadIdx.x == 0) atomicAdd(out, red[0] + red[1] + red[2] + red[3]);
}

__global__ void ternarize_kernel(const float* __restrict__ w, int n,
                                 const float* __restrict__ sum, bf16* __restrict__ out) {
  int i = blockIdx.x * blockDim.x + threadIdx.x;
  if (i >= n) return;
  float scale = fmaxf(*sum / (float)n, 1e-8f);
  float t = rintf(w[i] / scale);          // RNE == jnp.round
  t = fmaxf(-1.f, fminf(1.f, t));
  out[i] = (bf16)t;                        // {-1,0,1} exact in bf16
}

__global__ void split_x_kernel(const float* __restrict__ x, bf16* __restrict__ xh,
                               bf16* __restrict__ xl, int n) {
  int i = blockIdx.x * blockDim.x + threadIdx.x;
  if (i >= n) return;
  float v = x[i];
  bf16 h = (bf16)v;
  xh[i] = h;
  xl[i] = (bf16)(v - (float)h);
}

// ---------------- QKV GEMM: C[m][n] = sum_k (xh+xl)[m][k] * wt[n][k] ----------------
// 128x128 tile, BK=64, 4 waves (2x2), split-A double MFMA. Epilogue scatters
// q,k as hi/lo bf16 into [B,H,T,D]; v single bf16 into [B,H,T,D].

__launch_bounds__(256, 2)
__global__ void gemm_qkv_kernel(const bf16* __restrict__ xh, const bf16* __restrict__ xl,
                                const bf16* __restrict__ wt,
                                bf16* __restrict__ qh, bf16* __restrict__ ql,
                                bf16* __restrict__ kh, bf16* __restrict__ kl,
                                bf16* __restrict__ vv) {
  __shared__ __align__(16) bf16 Ah[128 * 64];
  __shared__ __align__(16) bf16 Al[128 * 64];
  __shared__ __align__(16) bf16 Bs[128 * 64];
  const int tid = threadIdx.x;
  const int lane = tid & 63, wid = tid >> 6;
  const int quad = lane >> 4, l16 = lane & 15;
  const int m0 = blockIdx.x * 128, n0 = blockIdx.y * 128;
  const int wm = (wid >> 1) * 64, wn = (wid & 1) * 64;
  f32v4 acc[4][4] = {};

  for (int kt = 0; kt < EMB / 64; ++kt) {
    __syncthreads();
    #pragma unroll
    for (int r = 0; r < 4; ++r) {
      int li = r * 256 + tid;
      int row = li >> 3, col = (li & 7) * 8;
      gload_lds16(xh + (size_t)(m0 + row) * EMB + kt * 64 + col, &Ah[li * 8]);
      gload_lds16(xl + (size_t)(m0 + row) * EMB + kt * 64 + col, &Al[li * 8]);
      gload_lds16(wt + (size_t)(n0 + row) * EMB + kt * 64 + col, &Bs[li * 8]);
    }
    __syncthreads();
    #pragma unroll
    for (int kk = 0; kk < 2; ++kk) {
      bf16v8 af[4], alf[4], bfr[4];
      #pragma unroll
      for (int i = 0; i < 4; ++i) {
        af[i]  = *(const bf16v8*)&Ah[(wm + i * 16 + l16) * 64 + kk * 32 + quad * 8];
        alf[i] = *(const bf16v8*)&Al[(wm + i * 16 + l16) * 64 + kk * 32 + quad * 8];
        bfr[i] = *(const bf16v8*)&Bs[(wn + i * 16 + l16) * 64 + kk * 32 + quad * 8];
      }
      #pragma unroll
      for (int i = 0; i < 4; ++i)
        #pragma unroll
        for (int j = 0; j < 4; ++j) {
          acc[i][j] = MFMA16(af[i],  bfr[j], acc[i][j]);
          acc[i][j] = MFMA16(alf[i], bfr[j], acc[i][j]);
        }
    }
  }
  // epilogue: D row = quad*4+r, col = l16
  #pragma unroll
  for (int i = 0; i < 4; ++i)
    #pragma unroll
    for (int j = 0; j < 4; ++j)
      #pragma unroll
      for (int r = 0; r < 4; ++r) {
        int m = m0 + wm + i * 16 + quad * 4 + r;
        int n = n0 + wn + j * 16 + l16;
        float c = acc[i][j][r];
        int b = m >> 11, t = m & (SEQ - 1);
        int region = n >> 10, c1 = n & 1023, h = c1 >> 6, d = c1 & 63;
        size_t idx = (((size_t)(b * NHEAD + h) * SEQ + t) << 6) + d;
        if (region == 0)      { bf16 hi = (bf16)c; qh[idx] = hi; ql[idx] = (bf16)(c - (float)hi); }
        else if (region == 1) { bf16 hi = (bf16)c; kh[idx] = hi; kl[idx] = (bf16)(c - (float)hi); }
        else                  { vv[idx] = (bf16)c; }
      }
}

// ---------------- V transpose: [B,H,T,D] -> [B,H,D,T] ----------------

__global__ void transpose_v_kernel(const bf16* __restrict__ v, bf16* __restrict__ vt) {
  __shared__ bf16 tile[64 * 72];
  const int tid = threadIdx.x;
  const int bh = blockIdx.y, t0 = blockIdx.x * 64;
  const size_t base = (size_t)bh * SEQ * HDIM;
  #pragma unroll
  for (int r = 0; r < 2; ++r) {
    int li = r * 256 + tid;
    int row = li >> 3, col = (li & 7) * 8;       // row = t, col = d
    bf16v8 val = *(const bf16v8*)(v + base + (size_t)(t0 + row) * HDIM + col);
    #pragma unroll
    for (int j = 0; j < 8; ++j) tile[(col + j) * 72 + row] = val[j];
  }
  __syncthreads();
  #pragma unroll
  for (int r = 0; r < 2; ++r) {
    int li = r * 256 + tid;
    int drow = li >> 3, tcol = (li & 7) * 8;     // row = d, col = t
    bf16v8 val;
    #pragma unroll
    for (int j = 0; j < 8; ++j) val[j] = tile[drow * 72 + tcol + j];
    *(bf16v8*)(vt + base + (size_t)drow * SEQ + t0 + tcol) = val;
  }
}

// ---------------- Flash attention: 64-row Q tile, 64-key KV tiles ----------------
// scores via 3-product hi/lo MFMA (fp32-accurate); online softmax per 16-lane
// row-group; P -> LDS (stride 72) -> A-operand; V^T staged from [B,H,D,T].

__launch_bounds__(256, 2)
__global__ void attn_kernel(const bf16* __restrict__ qh, const bf16* __restrict__ ql,
                            const bf16* __restrict__ kh, const bf16* __restrict__ kl,
                            const bf16* __restrict__ vt, bf16* __restrict__ o) {
  __shared__ __align__(16) bf16 Qh[64 * 64], Ql[64 * 64];
  __shared__ __align__(16) bf16 Kh[64 * 64], Kl[64 * 64];
  __shared__ __align__(16) bf16 Vt[64 * 64];
  __shared__ __align__(16) bf16 Pw[4][16 * 72];
  const int tid = threadIdx.x;
  const int lane = tid & 63, wid = tid >> 6;
  const int quad = lane >> 4, l16 = lane & 15;
  const int bh = blockIdx.y;
  const int q0 = blockIdx.x * 64;
  const size_t base = (size_t)bh * SEQ * HDIM;
  const float LOG2E = 1.44269504088896f;

  #pragma unroll
  for (int r = 0; r < 2; ++r) {
    int li = r * 256 + tid;
    int row = li >> 3, col = (li & 7) * 8;
    gload_lds16(qh + base + (size_t)(q0 + row) * HDIM + col, &Qh[li * 8]);
    gload_lds16(ql + base + (size_t)(q0 + row) * HDIM + col, &Ql[li * 8]);
  }
  __syncthreads();
  bf16v8 qhf[2], qlf[2];
  #pragma unroll
  for (int kk = 0; kk < 2; ++kk) {
    qhf[kk] = *(const bf16v8*)&Qh[(wid * 16 + l16) * 64 + kk * 32 + quad * 8];
    qlf[kk] = *(const bf16v8*)&Ql[(wid * 16 + l16) * 64 + kk * 32 + quad * 8];
  }

  f32v4 oacc[4] = {};
  float mrow[4], lrow[4];
  #pragma unroll
  for (int r = 0; r < 4; ++r) { mrow[r] = -1e30f; lrow[r] = 0.f; }

  const int ntiles = blockIdx.x + 1;
  for (int ktile = 0; ktile < ntiles; ++ktile) {
    const int k0 = ktile * 64;
    __syncthreads();
    #pragma unroll
    for (int r = 0; r < 2; ++r) {
      int li = r * 256 + tid;
      int row = li >> 3, col = (li & 7) * 8;
      gload_lds16(kh + base + (size_t)(k0 + row) * HDIM + col, &Kh[li * 8]);
      gload_lds16(kl + base + (size_t)(k0 + row) * HDIM + col, &Kl[li * 8]);
      gload_lds16(vt + base + (size_t)row * SEQ + k0 + col,    &Vt[li * 8]);
    }
    __syncthreads();

    f32v4 sacc[4] = {};
    #pragma unroll
    for (int kk = 0; kk < 2; ++kk) {
      bf16v8 khf[4], klf[4];
      #pragma unroll
      for (int nt = 0; nt < 4; ++nt) {
        khf[nt] = *(const bf16v8*)&Kh[(nt * 16 + l16) * 64 + kk * 32 + quad * 8];
        klf[nt] = *(const bf16v8*)&Kl[(nt * 16 + l16) * 64 + kk * 32 + quad * 8];
      }
      #pragma unroll
      for (int nt = 0; nt < 4; ++nt) {
        sacc[nt] = MFMA16(qhf[kk], khf[nt], sacc[nt]);
        sacc[nt] = MFMA16(qhf[kk], klf[nt], sacc[nt]);
        sacc[nt] = MFMA16(qlf[kk], khf[nt], sacc[nt]);
      }
    }

    const int qrow_base = q0 + wid * 16 + quad * 4;
    float sv[4][4];
    #pragma unroll
    for (int nt = 0; nt < 4; ++nt) {
      int key = k0 + nt * 16 + l16;
      #pragma unroll
      for (int r = 0; r < 4; ++r) {
        float s = sacc[nt][r] * 0.125f;           // / sqrt(64)
        if (key > qrow_base + r) s = -1e30f;      // causal mask
        sv[nt][r] = s;
      }
    }
    float mnew[4], alpha[4];
    #pragma unroll
    for (int r = 0; r < 4; ++r) {
      float mx = fmaxf(fmaxf(sv[0][r], sv[1][r]), fmaxf(sv[2][r], sv[3][r]));
      #pragma unroll
      for (int off = 8; off; off >>= 1) mx = fmaxf(mx, __shfl_xor(mx, off, 64));
      mnew[r] = fmaxf(mrow[r], mx);
      alpha[r] = exp2f((mrow[r] - mnew[r]) * LOG2E);
    }
    #pragma unroll
    for (int r = 0; r < 4; ++r) {
      float lsum = 0.f;
      #pragma unroll
      for (int nt = 0; nt < 4; ++nt) {
        float p = exp2f((sv[nt][r] - mnew[r]) * LOG2E);
        lsum += p;
        Pw[wid][(quad * 4 + r) * 72 + nt * 16 + l16] = (bf16)p;
      }
      #pragma unroll
      for (int off = 8; off; off >>= 1) lsum += __shfl_xor(lsum, off, 64);
      lrow[r] = lrow[r] * alpha[r] + lsum;
      mrow[r] = mnew[r];
    }
    #pragma unroll
    for (int dt = 0; dt < 4; ++dt)
      #pragma unroll
      for (int r = 0; r < 4; ++r) oacc[dt][r] *= alpha[r];

    // PV: A = P[q][key] (wave-private LDS slice, same-wave RAW ordered by lgkmcnt)
    #pragma unroll
    for (int kk = 0; kk < 2; ++kk) {
      bf16v8 pf = *(const bf16v8*)&Pw[wid][l16 * 72 + kk * 32 + quad * 8];
      #pragma unroll
      for (int dt = 0; dt < 4; ++dt) {
        bf16v8 vf = *(const bf16v8*)&Vt[(dt * 16 + l16) * 64 + kk * 32 + quad * 8];
        oacc[dt] = MFMA16(pf, vf, oacc[dt]);
      }
    }
  }

  const int b = bh >> 4, h = bh & 15;
  #pragma unroll
  for (int dt = 0; dt < 4; ++dt)
    #pragma unroll
    for (int r = 0; r < 4; ++r) {
      int q = q0 + wid * 16 + quad * 4 + r;
      int d = dt * 16 + l16;
      float val = oacc[dt][r] / lrow[r];
      o[((size_t)(b * SEQ + q)) * EMB + h * HDIM + d] = (bf16)val;
    }
}

// ---------------- out projection: out[m][n] = sum_k o[m][k] * wt[n][k] ----------------

__launch_bounds__(256, 2)
__global__ void gemm_out_kernel(const bf16* __restrict__ oin, const bf16* __restrict__ wt,
                                float* __restrict__ out) {
  __shared__ __align__(16) bf16 As_[128 * 64];
  __shared__ __align__(16) bf16 Bs_[128 * 64];
  const int tid = threadIdx.x;
  const int lane = tid & 63, wid = tid >> 6;
  const int quad = lane >> 4, l16 = lane & 15;
  const int m0 = blockIdx.x * 128, n0 = blockIdx.y * 128;
  const int wm = (wid >> 1) * 64, wn = (wid & 1) * 64;
  f32v4 acc[4][4] = {};

  for (int kt = 0; kt < EMB / 64; ++kt) {
    __syncthreads();
    #pragma unroll
    for (int r = 0; r < 4; ++r) {
      int li = r * 256 + tid;
      int row = li >> 3, col = (li & 7) * 8;
      gload_lds16(oin + (size_t)(m0 + row) * EMB + kt * 64 + col, &As_[li * 8]);
      gload_lds16(wt  + (size_t)(n0 + row) * EMB + kt * 64 + col, &Bs_[li * 8]);
    }
    __syncthreads();
    #pragma unroll
    for (int kk = 0; kk < 2; ++kk) {
      bf16v8 af[4], bfr[4];
      #pragma unroll
      for (int i = 0; i < 4; ++i) {
        af[i]  = *(const bf16v8*)&As_[(wm + i * 16 + l16) * 64 + kk * 32 + quad * 8];
        bfr[i] = *(const bf16v8*)&Bs_[(wn + i * 16 + l16) * 64 + kk * 32 + quad * 8];
      }
      #pragma unroll
      for (int i = 0; i < 4; ++i)
        #pragma unroll
        for (int j = 0; j < 4; ++j)
          acc[i][j] = MFMA16(af[i], bfr[j], acc[i][j]);
    }
  }
  #pragma unroll
  for (int i = 0; i < 4; ++i)
    #pragma unroll
    for (int j = 0; j < 4; ++j)
      #pragma unroll
      for (int r = 0; r < 4; ++r) {
        int m = m0 + wm + i * 16 + quad * 4 + r;
        int n = n0 + wn + j * 16 + l16;
        out[(size_t)m * EMB + n] = acc[i][j][r];
      }
}

// ---------------- launch ----------------

extern "C" void kernel_launch(void* const* d_in, const int* in_sizes, int n_in,
                              void* d_out, int out_size, void* d_ws, size_t ws_size,
                              hipStream_t stream) {
  const float* x     = (const float*)d_in[0];
  const float* w_qkv = (const float*)d_in[1];
  const float* w_out = (const float*)d_in[2];
  float* out = (float*)d_out;
  char* ws = (char*)d_ws;

  const size_t SZ = (size_t)MROWS * EMB * sizeof(bf16);   // 16.78 MB
  size_t off = 0;
  float* sums = (float*)ws;            off = 256;
  bf16* wq_t = (bf16*)(ws + off);      off += (size_t)NQKV * EMB * sizeof(bf16);
  bf16* wo_t = (bf16*)(ws + off);      off += (size_t)EMB * EMB * sizeof(bf16);
  bf16* xh   = (bf16*)(ws + off);      off += SZ;
  bf16* xl   = (bf16*)(ws + off);      off += SZ;
  bf16* qh   = (bf16*)(ws + off);      off += SZ;
  bf16* ql   = (bf16*)(ws + off);      off += SZ;
  bf16* kh   = (bf16*)(ws + off);      off += SZ;
  bf16* kl   = (bf16*)(ws + off);      off += SZ;
  bf16* vv   = (bf16*)(ws + off);      off += SZ;
  bf16* vt   = xh;   // x dead after gemm_qkv -> reuse
  bf16* ob   = xl;   // attention output (bf16), reuse
  (void)in_sizes; (void)n_in; (void)out_size; (void)ws_size;

  zero2_kernel<<<1, 2, 0, stream>>>(sums);
  abs_sum_kernel<<<256, 256, 0, stream>>>(w_qkv, NQKV * EMB, &sums[0]);
  abs_sum_kernel<<<256, 256, 0, stream>>>(w_out, EMB * EMB, &sums[1]);
  ternarize_kernel<<<(NQKV * EMB) / 256, 256, 0, stream>>>(w_qkv, NQKV * EMB, &sums[0], wq_t);
  ternarize_kernel<<<(EMB * EMB) / 256, 256, 0, stream>>>(w_out, EMB * EMB, &sums[1], wo_t);
  split_x_kernel<<<(MROWS * EMB) / 256, 256, 0, stream>>>(x, xh, xl, MROWS * EMB);
  gemm_qkv_kernel<<<dim3(MROWS / 128, NQKV / 128), 256, 0, stream>>>(xh, xl, wq_t, qh, ql, kh, kl, vv);
  transpose_v_kernel<<<dim3(SEQ / 64, BSZ * NHEAD), 256, 0, stream>>>(vv, vt);
  attn_kernel<<<dim3(SEQ / 64, BSZ * NHEAD), 256, 0, stream>>>(qh, ql, kh, kl, vt, ob);
  gemm_out_kernel<<<dim3(MROWS / 128, EMB / 128), 256, 0, stream>>>(ob, wo_t, out);
}

// Round 2
// 500.939 us; speedup vs baseline: 1.2489x; 1.2489x over previous
//
#include <hip/hip_runtime.h>
#include <hip/hip_bf16.h>

#define EMB   1024
#define NHEAD 16
#define HDIM  64
#define BSZ   4
#define SEQ   2048
#define MROWS (BSZ*SEQ)     // 8192
#define NQKV  (3*EMB)       // 3072

typedef __bf16 bf16;
typedef __bf16 bf16v8 __attribute__((ext_vector_type(8)));
typedef float  f32v4  __attribute__((ext_vector_type(4)));

#define MFMA16(a,b,c) __builtin_amdgcn_mfma_f32_16x16x32_bf16((a),(b),(c),0,0,0)

__device__ __forceinline__ void gload_lds16(const bf16* g, bf16* l) {
  __builtin_amdgcn_global_load_lds((const __attribute__((address_space(1))) void*)g,
                                   (__attribute__((address_space(3))) void*)l,
                                   16, 0, 0);
}

// ---------------- scale reduction + ternarize + split ----------------

__global__ void zero2_kernel(float* p) { p[threadIdx.x] = 0.f; }

__global__ void abs_sum_kernel(const float* __restrict__ w, int n, float* out) {
  float s = 0.f;
  for (int i = blockIdx.x * blockDim.x + threadIdx.x; i < n; i += gridDim.x * blockDim.x)
    s += fabsf(w[i]);
  #pragma unroll
  for (int off = 32; off; off >>= 1) s += __shfl_down(s, off, 64);
  __shared__ float red[4];
  int lane = threadIdx.x & 63, wid = threadIdx.x >> 6;
  if (lane == 0) red[wid] = s;
  __syncthreads();
  if (threadIdx.x == 0) atomicAdd(out, red[0] + red[1] + red[2] + red[3]);
}

__global__ void ternarize_kernel(const float* __restrict__ w, int n,
                                 const float* __restrict__ sum, bf16* __restrict__ out) {
  int i = blockIdx.x * blockDim.x + threadIdx.x;
  if (i >= n) return;
  float scale = fmaxf(*sum / (float)n, 1e-8f);
  float t = rintf(w[i] / scale);          // RNE == jnp.round
  t = fmaxf(-1.f, fminf(1.f, t));
  out[i] = (bf16)t;                        // {-1,0,1} exact in bf16
}

__global__ void split_x_kernel(const float* __restrict__ x, bf16* __restrict__ xh,
                               bf16* __restrict__ xl, int n) {
  int i = blockIdx.x * blockDim.x + threadIdx.x;
  if (i >= n) return;
  float v = x[i];
  bf16 h = (bf16)v;
  xh[i] = h;
  xl[i] = (bf16)(v - (float)h);
}

// ---------------- QKV GEMM (unchanged this round) ----------------

__launch_bounds__(256, 2)
__global__ void gemm_qkv_kernel(const bf16* __restrict__ xh, const bf16* __restrict__ xl,
                                const bf16* __restrict__ wt,
                                bf16* __restrict__ qh, bf16* __restrict__ ql,
                                bf16* __restrict__ kh, bf16* __restrict__ kl,
                                bf16* __restrict__ vv) {
  __shared__ __align__(16) bf16 Ah[128 * 64];
  __shared__ __align__(16) bf16 Al[128 * 64];
  __shared__ __align__(16) bf16 Bs[128 * 64];
  const int tid = threadIdx.x;
  const int lane = tid & 63, wid = tid >> 6;
  const int quad = lane >> 4, l16 = lane & 15;
  const int m0 = blockIdx.x * 128, n0 = blockIdx.y * 128;
  const int wm = (wid >> 1) * 64, wn = (wid & 1) * 64;
  f32v4 acc[4][4] = {};

  for (int kt = 0; kt < EMB / 64; ++kt) {
    __syncthreads();
    #pragma unroll
    for (int r = 0; r < 4; ++r) {
      int li = r * 256 + tid;
      int row = li >> 3, col = (li & 7) * 8;
      gload_lds16(xh + (size_t)(m0 + row) * EMB + kt * 64 + col, &Ah[li * 8]);
      gload_lds16(xl + (size_t)(m0 + row) * EMB + kt * 64 + col, &Al[li * 8]);
      gload_lds16(wt + (size_t)(n0 + row) * EMB + kt * 64 + col, &Bs[li * 8]);
    }
    __syncthreads();
    #pragma unroll
    for (int kk = 0; kk < 2; ++kk) {
      bf16v8 af[4], alf[4], bfr[4];
      #pragma unroll
      for (int i = 0; i < 4; ++i) {
        af[i]  = *(const bf16v8*)&Ah[(wm + i * 16 + l16) * 64 + kk * 32 + quad * 8];
        alf[i] = *(const bf16v8*)&Al[(wm + i * 16 + l16) * 64 + kk * 32 + quad * 8];
        bfr[i] = *(const bf16v8*)&Bs[(wn + i * 16 + l16) * 64 + kk * 32 + quad * 8];
      }
      #pragma unroll
      for (int i = 0; i < 4; ++i)
        #pragma unroll
        for (int j = 0; j < 4; ++j) {
          acc[i][j] = MFMA16(af[i],  bfr[j], acc[i][j]);
          acc[i][j] = MFMA16(alf[i], bfr[j], acc[i][j]);
        }
    }
  }
  #pragma unroll
  for (int i = 0; i < 4; ++i)
    #pragma unroll
    for (int j = 0; j < 4; ++j)
      #pragma unroll
      for (int r = 0; r < 4; ++r) {
        int m = m0 + wm + i * 16 + quad * 4 + r;
        int n = n0 + wn + j * 16 + l16;
        float c = acc[i][j][r];
        int b = m >> 11, t = m & (SEQ - 1);
        int region = n >> 10, c1 = n & 1023, h = c1 >> 6, d = c1 & 63;
        size_t idx = (((size_t)(b * NHEAD + h) * SEQ + t) << 6) + d;
        if (region == 0)      { bf16 hi = (bf16)c; qh[idx] = hi; ql[idx] = (bf16)(c - (float)hi); }
        else if (region == 1) { bf16 hi = (bf16)c; kh[idx] = hi; kl[idx] = (bf16)(c - (float)hi); }
        else                  { vv[idx] = (bf16)c; }
      }
}

// ---------------- V transpose: [B,H,T,D] -> [B,H,D,T] ----------------

__global__ void transpose_v_kernel(const bf16* __restrict__ v, bf16* __restrict__ vt) {
  __shared__ bf16 tile[64 * 72];
  const int tid = threadIdx.x;
  const int bh = blockIdx.y, t0 = blockIdx.x * 64;
  const size_t base = (size_t)bh * SEQ * HDIM;
  #pragma unroll
  for (int r = 0; r < 2; ++r) {
    int li = r * 256 + tid;
    int row = li >> 3, col = (li & 7) * 8;
    bf16v8 val = *(const bf16v8*)(v + base + (size_t)(t0 + row) * HDIM + col);
    #pragma unroll
    for (int j = 0; j < 8; ++j) tile[(col + j) * 72 + row] = val[j];
  }
  __syncthreads();
  #pragma unroll
  for (int r = 0; r < 2; ++r) {
    int li = r * 256 + tid;
    int drow = li >> 3, tcol = (li & 7) * 8;
    bf16v8 val;
    #pragma unroll
    for (int j = 0; j < 8; ++j) val[j] = tile[drow * 72 + tcol + j];
    *(bf16v8*)(vt + base + (size_t)drow * SEQ + t0 + tcol) = val;
  }
}

// ---------------- Flash attention v2 ----------------
// 512 threads = 8 waves, Q-tile 128 (wave w owns rows q0+16w..+15), KV tile 64.
// XOR chunk-swizzle (chunk c of row r stored at c^(r&7)) kills the 16-way
// fragment-read conflicts; Pw stride 68 kills the P-write conflicts.
// Heavy blocks first (qt = 15-blockIdx.x); wave-uniform causal skip.

__launch_bounds__(512, 4)
__global__ void attn_kernel(const bf16* __restrict__ qh, const bf16* __restrict__ ql,
                            const bf16* __restrict__ kh, const bf16* __restrict__ kl,
                            const bf16* __restrict__ vt, bf16* __restrict__ o) {
  __shared__ __align__(16) bf16 Qh[128 * 64], Ql[128 * 64];
  __shared__ __align__(16) bf16 Kh[64 * 64], Kl[64 * 64];
  __shared__ __align__(16) bf16 Vt[64 * 64];
  __shared__ __align__(16) bf16 Pw[8][16 * 68];
  const int tid = threadIdx.x;
  const int lane = tid & 63, wid = tid >> 6;
  const int quad = lane >> 4, l16 = lane & 15;
  const int xs = l16 & 7;                       // fragment-read swizzle
  const int bh = blockIdx.y;
  const int qt = (int)gridDim.x - 1 - (int)blockIdx.x;   // heavy first
  const int q0 = qt * 128;
  const size_t base = (size_t)bh * SEQ * HDIM;
  const float LOG2E = 1.44269504088896f;

  // stage Q (hi+lo), swizzled
  #pragma unroll
  for (int r = 0; r < 2; ++r) {
    int li = r * 512 + tid;
    int row = li >> 3, cg = (li & 7) ^ (row & 7);
    gload_lds16(qh + base + (size_t)(q0 + row) * HDIM + cg * 8, &Qh[li * 8]);
    gload_lds16(ql + base + (size_t)(q0 + row) * HDIM + cg * 8, &Ql[li * 8]);
  }
  __syncthreads();
  bf16v8 qhf[2], qlf[2];
  #pragma unroll
  for (int kk = 0; kk < 2; ++kk) {
    int off = (wid * 16 + l16) * 64 + (((kk << 2) | quad) ^ xs) * 8;
    qhf[kk] = *(const bf16v8*)&Qh[off];
    qlf[kk] = *(const bf16v8*)&Ql[off];
  }

  f32v4 oacc[4] = {};
  float mrow[4], lrow[4];
  #pragma unroll
  for (int r = 0; r < 4; ++r) { mrow[r] = -1e30f; lrow[r] = 0.f; }

  const int qrow_hi = q0 + wid * 16 + 15;       // wave-uniform causal limit
  const int ntiles = 2 * qt + 2;
  for (int ktile = 0; ktile < ntiles; ++ktile) {
    const int k0 = ktile * 64;
    __syncthreads();
    {
      int row = tid >> 3, cg = (tid & 7) ^ (row & 7);
      gload_lds16(kh + base + (size_t)(k0 + row) * HDIM + cg * 8, &Kh[(size_t)tid * 8]);
      gload_lds16(kl + base + (size_t)(k0 + row) * HDIM + cg * 8, &Kl[(size_t)tid * 8]);
      gload_lds16(vt + base + (size_t)row * SEQ + k0 + cg * 8,    &Vt[(size_t)tid * 8]);
    }
    __syncthreads();
    if (k0 > qrow_hi) continue;                  // fully-masked tile for this wave

    f32v4 sacc[4] = {};
    #pragma unroll
    for (int kk = 0; kk < 2; ++kk) {
      const int co = (((kk << 2) | quad) ^ xs) * 8;
      bf16v8 khf[4], klf[4];
      #pragma unroll
      for (int nt = 0; nt < 4; ++nt) {
        khf[nt] = *(const bf16v8*)&Kh[(nt * 16 + l16) * 64 + co];
        klf[nt] = *(const bf16v8*)&Kl[(nt * 16 + l16) * 64 + co];
      }
      #pragma unroll
      for (int nt = 0; nt < 4; ++nt) {
        sacc[nt] = MFMA16(qhf[kk], khf[nt], sacc[nt]);
        sacc[nt] = MFMA16(qhf[kk], klf[nt], sacc[nt]);
        sacc[nt] = MFMA16(qlf[kk], khf[nt], sacc[nt]);
      }
    }

    const int qrow_base = q0 + wid * 16 + quad * 4;
    float sv[4][4];
    #pragma unroll
    for (int nt = 0; nt < 4; ++nt) {
      int key = k0 + nt * 16 + l16;
      #pragma unroll
      for (int r = 0; r < 4; ++r) {
        float s = sacc[nt][r] * 0.125f;           // / sqrt(64)
        if (key > qrow_base + r) s = -1e30f;      // causal mask
        sv[nt][r] = s;
      }
    }
    float mnew[4], alpha[4];
    #pragma unroll
    for (int r = 0; r < 4; ++r) {
      float mx = fmaxf(fmaxf(sv[0][r], sv[1][r]), fmaxf(sv[2][r], sv[3][r]));
      #pragma unroll
      for (int off = 8; off; off >>= 1) mx = fmaxf(mx, __shfl_xor(mx, off, 64));
      mnew[r] = fmaxf(mrow[r], mx);
      alpha[r] = exp2f((mrow[r] - mnew[r]) * LOG2E);
    }
    #pragma unroll
    for (int r = 0; r < 4; ++r) {
      float lsum = 0.f;
      #pragma unroll
      for (int nt = 0; nt < 4; ++nt) {
        float p = exp2f((sv[nt][r] - mnew[r]) * LOG2E);
        lsum += p;
        Pw[wid][(quad * 4 + r) * 68 + nt * 16 + l16] = (bf16)p;
      }
      #pragma unroll
      for (int off = 8; off; off >>= 1) lsum += __shfl_xor(lsum, off, 64);
      lrow[r] = lrow[r] * alpha[r] + lsum;
      mrow[r] = mnew[r];
    }
    #pragma unroll
    for (int dt = 0; dt < 4; ++dt)
      #pragma unroll
      for (int r = 0; r < 4; ++r) oacc[dt][r] *= alpha[r];

    // PV: A = P (wave-private LDS slice), B = V^T tile
    #pragma unroll
    for (int kk = 0; kk < 2; ++kk) {
      bf16v8 pf = *(const bf16v8*)&Pw[wid][l16 * 68 + kk * 32 + quad * 8];
      const int co = (((kk << 2) | quad) ^ xs) * 8;
      #pragma unroll
      for (int dt = 0; dt < 4; ++dt) {
        bf16v8 vf = *(const bf16v8*)&Vt[(dt * 16 + l16) * 64 + co];
        oacc[dt] = MFMA16(pf, vf, oacc[dt]);
      }
    }
  }

  const int b = bh >> 4, h = bh & 15;
  #pragma unroll
  for (int dt = 0; dt < 4; ++dt)
    #pragma unroll
    for (int r = 0; r < 4; ++r) {
      int q = q0 + wid * 16 + quad * 4 + r;
      int d = dt * 16 + l16;
      float val = oacc[dt][r] / lrow[r];
      o[((size_t)(b * SEQ + q)) * EMB + h * HDIM + d] = (bf16)val;
    }
}

// ---------------- out projection (unchanged) ----------------

__launch_bounds__(256, 2)
__global__ void gemm_out_kernel(const bf16* __restrict__ oin, const bf16* __restrict__ wt,
                                float* __restrict__ out) {
  __shared__ __align__(16) bf16 As_[128 * 64];
  __shared__ __align__(16) bf16 Bs_[128 * 64];
  const int tid = threadIdx.x;
  const int lane = tid & 63, wid = tid >> 6;
  const int quad = lane >> 4, l16 = lane & 15;
  const int m0 = blockIdx.x * 128, n0 = blockIdx.y * 128;
  const int wm = (wid >> 1) * 64, wn = (wid & 1) * 64;
  f32v4 acc[4][4] = {};

  for (int kt = 0; kt < EMB / 64; ++kt) {
    __syncthreads();
    #pragma unroll
    for (int r = 0; r < 4; ++r) {
      int li = r * 256 + tid;
      int row = li >> 3, col = (li & 7) * 8;
      gload_lds16(oin + (size_t)(m0 + row) * EMB + kt * 64 + col, &As_[li * 8]);
      gload_lds16(wt  + (size_t)(n0 + row) * EMB + kt * 64 + col, &Bs_[li * 8]);
    }
    __syncthreads();
    #pragma unroll
    for (int kk = 0; kk < 2; ++kk) {
      bf16v8 af[4], bfr[4];
      #pragma unroll
      for (int i = 0; i < 4; ++i) {
        af[i]  = *(const bf16v8*)&As_[(wm + i * 16 + l16) * 64 + kk * 32 + quad * 8];
        bfr[i] = *(const bf16v8*)&Bs_[(wn + i * 16 + l16) * 64 + kk * 32 + quad * 8];
      }
      #pragma unroll
      for (int i = 0; i < 4; ++i)
        #pragma unroll
        for (int j = 0; j < 4; ++j)
          acc[i][j] = MFMA16(af[i], bfr[j], acc[i][j]);
    }
  }
  #pragma unroll
  for (int i = 0; i < 4; ++i)
    #pragma unroll
    for (int j = 0; j < 4; ++j)
      #pragma unroll
      for (int r = 0; r < 4; ++r) {
        int m = m0 + wm + i * 16 + quad * 4 + r;
        int n = n0 + wn + j * 16 + l16;
        out[(size_t)m * EMB + n] = acc[i][j][r];
      }
}

// ---------------- launch ----------------

extern "C" void kernel_launch(void* const* d_in, const int* in_sizes, int n_in,
                              void* d_out, int out_size, void* d_ws, size_t ws_size,
                              hipStream_t stream) {
  const float* x     = (const float*)d_in[0];
  const float* w_qkv = (const float*)d_in[1];
  const float* w_out = (const float*)d_in[2];
  float* out = (float*)d_out;
  char* ws = (char*)d_ws;

  const size_t SZ = (size_t)MROWS * EMB * sizeof(bf16);   // 16.78 MB
  size_t off = 0;
  float* sums = (float*)ws;            off = 256;
  bf16* wq_t = (bf16*)(ws + off);      off += (size_t)NQKV * EMB * sizeof(bf16);
  bf16* wo_t = (bf16*)(ws + off);      off += (size_t)EMB * EMB * sizeof(bf16);
  bf16* xh   = (bf16*)(ws + off);      off += SZ;
  bf16* xl   = (bf16*)(ws + off);      off += SZ;
  bf16* qh   = (bf16*)(ws + off);      off += SZ;
  bf16* ql   = (bf16*)(ws + off);      off += SZ;
  bf16* kh   = (bf16*)(ws + off);      off += SZ;
  bf16* kl   = (bf16*)(ws + off);      off += SZ;
  bf16* vv   = (bf16*)(ws + off);      off += SZ;
  bf16* vt   = xh;   // x dead after gemm_qkv -> reuse
  bf16* ob   = xl;   // attention output (bf16), reuse
  (void)in_sizes; (void)n_in; (void)out_size; (void)ws_size;

  zero2_kernel<<<1, 2, 0, stream>>>(sums);
  abs_sum_kernel<<<256, 256, 0, stream>>>(w_qkv, NQKV * EMB, &sums[0]);
  abs_sum_kernel<<<256, 256, 0, stream>>>(w_out, EMB * EMB, &sums[1]);
  ternarize_kernel<<<(NQKV * EMB) / 256, 256, 0, stream>>>(w_qkv, NQKV * EMB, &sums[0], wq_t);
  ternarize_kernel<<<(EMB * EMB) / 256, 256, 0, stream>>>(w_out, EMB * EMB, &sums[1], wo_t);
  split_x_kernel<<<(MROWS * EMB) / 256, 256, 0, stream>>>(x, xh, xl, MROWS * EMB);
  gemm_qkv_kernel<<<dim3(MROWS / 128, NQKV / 128), 256, 0, stream>>>(xh, xl, wq_t, qh, ql, kh, kl, vv);
  transpose_v_kernel<<<dim3(SEQ / 64, BSZ * NHEAD), 256, 0, stream>>>(vv, vt);
  attn_kernel<<<dim3(SEQ / 128, BSZ * NHEAD), 512, 0, stream>>>(qh, ql, kh, kl, vt, ob);
  gemm_out_kernel<<<dim3(MROWS / 128, EMB / 128), 256, 0, stream>>>(ob, wo_t, out);
}